// Round 1
// baseline (186.372 us; speedup 1.0000x reference)
//
#include <hip/hip_runtime.h>
#include <hip/hip_cooperative_groups.h>

namespace cg = cooperative_groups;

#define Bv 32
#define Av 3
#define Gv 52
#define Cv 80
#define Nv 512
#define Mv (Bv*Av*Gv*Gv)   // 259584
#define NBLK 256
#define NTHR 256

// fast ln with the reference's clip(log, -100)
__device__ __forceinline__ float flog(float x) {
    return fmaxf(__logf(x), -100.0f);
}

__device__ __forceinline__ float wred(float v) {
    #pragma unroll
    for (int o = 32; o > 0; o >>= 1) v += __shfl_down(v, o, 64);
    return v;   // valid on lane 0 of each wave
}

// partials layout per block (stride 16 floats):
// 0:bulk_noobj_sum 1:lx 2:ly 3:lw 4:lh 5:conf_obj 6:cls_corr 7:conf_sub
// 8:cls_base 9:n_obj 10:n_kill

__device__ __forceinline__ void decode_target(
    const float* __restrict__ tp, const float* s_anc,
    int& cell, int& pairkey, int kk[3], int& best_out,
    float& gx, float& gy, float& gw, float& gh)
{
    gx = tp[2] * Gv; gy = tp[3] * Gv; gw = tp[4] * Gv; gh = tp[5] * Gv;
    int si  = (int)tp[0];
    int lab = (int)tp[1];
    int gi = (int)floorf(gx), gj = (int)floorf(gy);
    float iou[3];
    #pragma unroll
    for (int a = 0; a < 3; ++a) {
        float aw = s_anc[2*a], ah = s_anc[2*a+1];
        float inter = fminf(aw, gw) * fminf(ah, gh);
        float uni = aw*ah + 1e-16f + gw*gh - inter;
        iou[a] = inter / uni;
    }
    int best = 0; float bi = iou[0];
    if (iou[1] > bi) { best = 1; bi = iou[1]; }
    if (iou[2] > bi) { best = 2; bi = iou[2]; }
    best_out = best;
    cell = ((si*Av + best)*Gv + gj)*Gv + gi;
    pairkey = cell * Cv + lab;
    #pragma unroll
    for (int a = 0; a < 3; ++a) {
        bool kill = (a == best) || (iou[a] > 0.5f);
        kk[a] = kill ? ((((si*Av + a)*Gv + gj)*Gv + gi) + 1) : 0;
    }
}

__global__ __launch_bounds__(NTHR) void fused_kernel(
    const float* __restrict__ pred_cls,
    const float* __restrict__ center_x,
    const float* __restrict__ center_y,
    const float* __restrict__ width_,
    const float* __restrict__ height_,
    const float* __restrict__ confidence,
    const float* __restrict__ anchors,
    const float* __restrict__ target,
    float* __restrict__ partials,
    float* __restrict__ out)
{
    __shared__ int   s_cell[Nv];
    __shared__ int   s_pair[Nv];
    __shared__ int   s_kill[3*Nv];
    __shared__ int   s_flag[12];     // [0,1] rep blocked; [2,3] pair blocked; [4..9] kill blocked (j*3+a)
    __shared__ int   s_repcell[2];
    __shared__ float s_acc[11];
    __shared__ float s_anc[6];
    __shared__ float s_r[4][11];     // epilogue cross-wave reduce (block 0 only)

    const int t = threadIdx.x;

    // ---- issue the bulk confidence load FIRST so HBM latency hides under
    //      the LDS decode/dedup phases (each thread owns at most one float4:
    //      NBLK*NTHR = 65536 >= Mv/4 = 64896) ----
    const int ci = blockIdx.x * NTHR + t;
    const bool hasc = ci < (Mv/4);
    float4 cv;
    if (hasc) cv = ((const float4*)confidence)[ci];

    if (t < 6)  s_anc[t]  = anchors[t];
    if (t < 12) s_flag[t] = 0;
    if (t < 11) s_acc[t]  = 0.f;
    __syncthreads();

    // ---- redundant decode of all 512 targets into LDS (2 per thread) ----
    for (int n = t; n < Nv; n += NTHR) {
        int cell, pair, kk[3], best; float gx, gy, gw, gh;
        decode_target(target + n*6, s_anc, cell, pair, kk, best, gx, gy, gw, gh);
        s_cell[n] = cell;
        s_pair[n] = pair;
        s_kill[3*n+0] = kk[0]; s_kill[3*n+1] = kk[1]; s_kill[3*n+2] = kk[2];
    }
    __syncthreads();

    // ---- dedup scan for this block's two owned targets ----
    const int n0 = 2 * blockIdx.x;          // owns n0, n0+1
    const int c0 = s_cell[n0],   c1 = s_cell[n0+1];
    const int p0 = s_pair[n0],   p1 = s_pair[n0+1];
    int k0[3], k1[3];
    #pragma unroll
    for (int a = 0; a < 3; ++a) { k0[a] = s_kill[3*n0+a]; k1[a] = s_kill[3*n0+3+a]; }

    for (int m = t; m < Nv; m += NTHR) {
        int cm = s_cell[m];
        if (m > n0     && cm == c0) s_flag[0] = 1;   // rep = max-n (last .set wins)
        if (m > n0 + 1 && cm == c1) s_flag[1] = 1;
        int pm = s_pair[m];
        if (m < n0     && pm == p0) s_flag[2] = 1;   // pair handled by min-n
        if (m < n0 + 1 && pm == p1) s_flag[3] = 1;
        #pragma unroll
        for (int a = 0; a < 3; ++a) {
            int km = s_kill[3*m + a];
            if (!km) continue;
            int idx = 3*m + a;
            #pragma unroll
            for (int a2 = 0; a2 < 3; ++a2) {
                if (idx < 3*n0 + a2     && km == k0[a2]) s_flag[4 + a2] = 1;
                if (idx < 3*(n0+1) + a2 && km == k1[a2]) s_flag[7 + a2] = 1;
            }
        }
    }
    __syncthreads();

    // ---- owned-target contributions (thread 0 -> n0, thread 64 -> n0+1) ----
    if (t == 0 || t == 64) {
        const int j = t >> 6;
        const int n = n0 + j;
        int cell, pair, kk[3], best; float gx, gy, gw, gh;
        decode_target(target + n*6, s_anc, cell, pair, kk, best, gx, gy, gw, gh);

        int repv = 0;
        if (!s_flag[j]) {                       // I'm this cell's representative
            float tx = gx - floorf(gx);
            float ty = gy - floorf(gy);
            float tw = __logf(gw / s_anc[2*best]   + 1e-16f);
            float th = __logf(gh / s_anc[2*best+1] + 1e-16f);
            float dx = center_x[cell] - tx;
            float dy = center_y[cell] - ty;
            float dw = width_[cell]  - tw;
            float dh = height_[cell] - th;
            atomicAdd(&s_acc[1], dx*dx);
            atomicAdd(&s_acc[2], dy*dy);
            atomicAdd(&s_acc[3], dw*dw);
            atomicAdd(&s_acc[4], dh*dh);
            atomicAdd(&s_acc[5], -flog(confidence[cell]));
            atomicAdd(&s_acc[9], 1.f);          // n_obj
            repv = 1;
        }
        s_repcell[j] = repv ? cell : -1;

        if (!s_flag[2 + j]) {                   // first occurrence of (cell,label)
            float p = pred_cls[(size_t)pair];
            atomicAdd(&s_acc[6], -flog(p) + flog(1.f - p));
        }

        float csub = 0.f, nk = 0.f;
        #pragma unroll
        for (int a = 0; a < 3; ++a) {
            int kc = kk[a];
            if (kc && !s_flag[4 + 3*j + a]) {   // first occurrence of killed cell
                csub += -flog(1.f - confidence[kc - 1]);
                nk += 1.f;
            }
        }
        if (nk != 0.f) { atomicAdd(&s_acc[7], csub); atomicAdd(&s_acc[10], nk); }
    }
    __syncthreads();

    // ---- cls base for owned representative cells (80 classes each) ----
    {
        const int j = t >> 7;                   // threads 0-127 -> rep0, 128-255 -> rep1
        const int c = t & 127;
        float v = 0.f;
        int cell = s_repcell[j];
        if (cell >= 0 && c < Cv)
            v = -flog(1.f - pred_cls[(size_t)cell * Cv + c]);
        v = wred(v);
        if ((t & 63) == 0) atomicAdd(&s_acc[8], v);
    }

    // ---- bulk: sum of -clip(log(1-conf)) over ALL cells (data loaded at top) ----
    {
        float local = 0.f;
        if (hasc)
            local = -(flog(1.f - cv.x) + flog(1.f - cv.y) +
                      flog(1.f - cv.z) + flog(1.f - cv.w));
        local = wred(local);
        if ((t & 63) == 0) atomicAdd(&s_acc[0], local);
    }
    __syncthreads();

    // ---- publish this block's partials, then grid-wide sync ----
    if (t < 11) partials[blockIdx.x * 16 + t] = s_acc[t];
    __threadfence();                  // release: make partials visible device-wide
    cg::this_grid().sync();

    // ---- epilogue reduce (block 0 only; was reduce_kernel) ----
    if (blockIdx.x == 0) {
        __threadfence();              // acquire side
        float v[11];
        #pragma unroll
        for (int j = 0; j < 11; ++j) v[j] = partials[t * 16 + j];
        #pragma unroll
        for (int j = 0; j < 11; ++j) v[j] = wred(v[j]);
        const int lane = t & 63, w = t >> 6;
        if (lane == 0) {
            #pragma unroll
            for (int j = 0; j < 11; ++j) s_r[w][j] = v[j];
        }
        __syncthreads();
        if (t == 0) {
            float a[11];
            #pragma unroll
            for (int j = 0; j < 11; ++j)
                a[j] = s_r[0][j] + s_r[1][j] + s_r[2][j] + s_r[3][j];
            float n_obj   = a[9];
            float n_kill  = a[10];
            float inv_obj = 1.f / n_obj;
            float n_noobj = (float)Mv - n_kill;
            float loss_coord = (a[1] + a[2] + a[3] + a[4]) * inv_obj;
            float loss_conf  = a[5] * inv_obj + 100.f * (a[0] - a[7]) / n_noobj;
            float loss_cls   = (a[8] + a[6]) * inv_obj / (float)Cv;
            out[0] = loss_coord + loss_conf + loss_cls;
        }
    }
}

extern "C" void kernel_launch(void* const* d_in, const int* in_sizes, int n_in,
                              void* d_out, int out_size, void* d_ws, size_t ws_size,
                              hipStream_t stream) {
    // setup_inputs order: 0:pred_boxes(unused) 1:pred_cls 2:center_x 3:center_y
    //                     4:width 5:height 6:confidence 7:anchors 8:target
    const float* pred_cls   = (const float*)d_in[1];
    const float* center_x   = (const float*)d_in[2];
    const float* center_y   = (const float*)d_in[3];
    const float* width_     = (const float*)d_in[4];
    const float* height_    = (const float*)d_in[5];
    const float* confidence = (const float*)d_in[6];
    const float* anchors    = (const float*)d_in[7];
    const float* target     = (const float*)d_in[8];
    float* partials = (float*)d_ws;   // 256 blocks × 16 floats = 16 KB
    float* out      = (float*)d_out;

    void* args[] = {
        (void*)&pred_cls, (void*)&center_x, (void*)&center_y, (void*)&width_,
        (void*)&height_, (void*)&confidence, (void*)&anchors, (void*)&target,
        (void*)&partials, (void*)&out
    };
    hipLaunchCooperativeKernel((const void*)fused_kernel,
                               dim3(NBLK), dim3(NTHR), args, 0, stream);
}

// Round 2
// 126.349 us; speedup vs baseline: 1.4751x; 1.4751x over previous
//
#include <hip/hip_runtime.h>

#define Bv 32
#define Av 3
#define Gv 52
#define Cv 80
#define Nv 512
#define Mv (Bv*Av*Gv*Gv)   // 259584
#define NBLK 256
#define NTHR 256

// fast ln with the reference's clip(log, -100)
__device__ __forceinline__ float flog(float x) {
    return fmaxf(__logf(x), -100.0f);
}

__device__ __forceinline__ float wred(float v) {
    #pragma unroll
    for (int o = 32; o > 0; o >>= 1) v += __shfl_down(v, o, 64);
    return v;   // valid on lane 0 of each wave
}

// partials layout per block (stride 16 floats):
// 0:bulk_noobj_sum 1:lx 2:ly 3:lw 4:lh 5:conf_obj 6:cls_corr 7:conf_sub
// 8:cls_base 9:n_obj 10:n_kill

__device__ __forceinline__ void decode_target(
    const float* __restrict__ tp, const float* anc,
    int& cell, int& pairkey, int kk[3], int& best_out,
    float& gx, float& gy, float& gw, float& gh)
{
    // target row is 6 floats, 8B-aligned -> three float2 loads
    float2 t01 = *(const float2*)(tp);
    float2 t23 = *(const float2*)(tp + 2);
    float2 t45 = *(const float2*)(tp + 4);
    gx = t23.x * Gv; gy = t23.y * Gv; gw = t45.x * Gv; gh = t45.y * Gv;
    int si  = (int)t01.x;
    int lab = (int)t01.y;
    int gi = (int)floorf(gx), gj = (int)floorf(gy);
    float iou[3];
    #pragma unroll
    for (int a = 0; a < 3; ++a) {
        float aw = anc[2*a], ah = anc[2*a+1];
        float inter = fminf(aw, gw) * fminf(ah, gh);
        float uni = aw*ah + 1e-16f + gw*gh - inter;
        iou[a] = inter / uni;
    }
    int best = 0; float bi = iou[0];
    if (iou[1] > bi) { best = 1; bi = iou[1]; }
    if (iou[2] > bi) { best = 2; bi = iou[2]; }
    best_out = best;
    cell = ((si*Av + best)*Gv + gj)*Gv + gi;
    pairkey = cell * Cv + lab;
    #pragma unroll
    for (int a = 0; a < 3; ++a) {
        bool kill = (a == best) || (iou[a] > 0.5f);
        kk[a] = kill ? ((((si*Av + a)*Gv + gj)*Gv + gi) + 1) : 0;
    }
}

__global__ __launch_bounds__(NTHR) void main_kernel(
    const float* __restrict__ pred_cls,
    const float* __restrict__ center_x,
    const float* __restrict__ center_y,
    const float* __restrict__ width_,
    const float* __restrict__ height_,
    const float* __restrict__ confidence,
    const float* __restrict__ anchors,
    const float* __restrict__ target,
    float* __restrict__ partials)
{
    __shared__ int   s_cell[Nv];
    __shared__ int   s_pair[Nv];
    __shared__ int   s_kill[3*Nv];
    __shared__ int   s_flag[12];     // [0,1] rep blocked; [2,3] pair blocked; [4..9] kill blocked (j*3+a)
    __shared__ float s_acc[11];
    __shared__ float s_anc[6];

    const int t  = threadIdx.x;
    const int n0 = 2 * blockIdx.x;          // this block owns targets n0, n0+1

    // ---- bulk confidence load FIRST: 1 float4/thread, stays in flight
    //      (NBLK*NTHR = 65536 >= Mv/4 = 64896) ----
    const int ci = blockIdx.x * NTHR + t;
    const bool hasc = ci < (Mv/4);
    float4 cv = make_float4(0.f, 0.f, 0.f, 0.f);
    if (hasc) cv = ((const float4*)confidence)[ci];

    if (t < 6)  s_anc[t]  = anchors[t];
    if (t < 12) s_flag[t] = 0;
    if (t < 11) s_acc[t]  = 0.f;

    // ---- owner threads (0 -> n0, 64 -> n0+1): decode own target NOW using
    //      anchors straight from global (no s_anc barrier dependency), and
    //      issue every scattered load so HBM latency hides under the
    //      communal decode + dedup scan that follows ----
    const bool owner = (t == 0 || t == 64);
    float la[6];
    int own_cell = 0, own_pair = 0, own_kk[3] = {0,0,0}, own_best = 0;
    float own_gx = 0.f, own_gy = 0.f, own_gw = 0.f, own_gh = 0.f;
    float pre_cx = 0.f, pre_cy = 0.f, pre_w = 0.f, pre_h = 0.f;
    float pre_conf = 0.f, pre_pcls = 0.5f;
    float pre_kconf[3] = {0.f, 0.f, 0.f};
    if (owner) {
        #pragma unroll
        for (int i = 0; i < 6; ++i) la[i] = anchors[i];
        const int j = t >> 6;
        decode_target(target + (n0 + j)*6, la, own_cell, own_pair, own_kk,
                      own_best, own_gx, own_gy, own_gw, own_gh);
        pre_cx   = center_x[own_cell];
        pre_cy   = center_y[own_cell];
        pre_w    = width_[own_cell];
        pre_h    = height_[own_cell];
        pre_conf = confidence[own_cell];
        pre_pcls = pred_cls[(size_t)own_pair];
        #pragma unroll
        for (int a = 0; a < 3; ++a)
            if (own_kk[a]) pre_kconf[a] = confidence[own_kk[a] - 1];
    }
    __syncthreads();

    // ---- redundant decode of all 512 targets into LDS (2 per thread) ----
    for (int n = t; n < Nv; n += NTHR) {
        int cell, pair, kk[3], best; float gx, gy, gw, gh;
        decode_target(target + n*6, s_anc, cell, pair, kk, best, gx, gy, gw, gh);
        s_cell[n] = cell;
        s_pair[n] = pair;
        s_kill[3*n+0] = kk[0]; s_kill[3*n+1] = kk[1]; s_kill[3*n+2] = kk[2];
    }
    __syncthreads();

    // ---- speculative cls-base row load (address needs only s_cell);
    //      issued BEFORE the scan so it lands while the scan runs.
    //      Use gated by rep-flag after the scan barrier. ----
    const int jj = t >> 7;                  // threads 0-127 -> target n0, 128-255 -> n0+1
    const int cc = t & 127;
    const int repcell = s_cell[n0 + jj];
    float pj = 0.f;
    if (cc < Cv) pj = pred_cls[(size_t)repcell * Cv + cc];

    // ---- dedup scan for this block's two owned targets ----
    const int c0 = s_cell[n0],   c1 = s_cell[n0+1];
    const int p0 = s_pair[n0],   p1 = s_pair[n0+1];
    int k0[3], k1[3];
    #pragma unroll
    for (int a = 0; a < 3; ++a) { k0[a] = s_kill[3*n0+a]; k1[a] = s_kill[3*n0+3+a]; }

    for (int m = t; m < Nv; m += NTHR) {
        int cm = s_cell[m];
        if (m > n0     && cm == c0) s_flag[0] = 1;   // rep = max-n (last .set wins)
        if (m > n0 + 1 && cm == c1) s_flag[1] = 1;
        int pm = s_pair[m];
        if (m < n0     && pm == p0) s_flag[2] = 1;   // pair handled by min-n
        if (m < n0 + 1 && pm == p1) s_flag[3] = 1;
        #pragma unroll
        for (int a = 0; a < 3; ++a) {
            int km = s_kill[3*m + a];
            if (!km) continue;
            int idx = 3*m + a;
            #pragma unroll
            for (int a2 = 0; a2 < 3; ++a2) {
                if (idx < 3*n0 + a2     && km == k0[a2]) s_flag[4 + a2] = 1;
                if (idx < 3*(n0+1) + a2 && km == k1[a2]) s_flag[7 + a2] = 1;
            }
        }
    }
    __syncthreads();

    // ============ single accumulation region (all phases merged) ============

    // ---- owned-target contributions with pre-loaded values ----
    if (owner) {
        const int j = t >> 6;
        if (!s_flag[j]) {                       // I'm this cell's representative
            float tx = own_gx - floorf(own_gx);
            float ty = own_gy - floorf(own_gy);
            float tw = __logf(own_gw / la[2*own_best]   + 1e-16f);
            float th = __logf(own_gh / la[2*own_best+1] + 1e-16f);
            float dx = pre_cx - tx;
            float dy = pre_cy - ty;
            float dw = pre_w  - tw;
            float dh = pre_h  - th;
            atomicAdd(&s_acc[1], dx*dx);
            atomicAdd(&s_acc[2], dy*dy);
            atomicAdd(&s_acc[3], dw*dw);
            atomicAdd(&s_acc[4], dh*dh);
            atomicAdd(&s_acc[5], -flog(pre_conf));
            atomicAdd(&s_acc[9], 1.f);          // n_obj
        }

        if (!s_flag[2 + j]) {                   // first occurrence of (cell,label)
            atomicAdd(&s_acc[6], -flog(pre_pcls) + flog(1.f - pre_pcls));
        }

        float csub = 0.f, nk = 0.f;
        #pragma unroll
        for (int a = 0; a < 3; ++a) {
            if (own_kk[a] && !s_flag[4 + 3*j + a]) {   // first occurrence of killed cell
                csub += -flog(1.f - pre_kconf[a]);
                nk += 1.f;
            }
        }
        if (nk != 0.f) { atomicAdd(&s_acc[7], csub); atomicAdd(&s_acc[10], nk); }
    }

    // ---- cls base: rep-gated use of the speculative row load ----
    {
        float v = 0.f;
        if (!s_flag[jj] && cc < Cv)
            v = -flog(1.f - pj);
        v = wred(v);
        if ((t & 63) == 0) atomicAdd(&s_acc[8], v);
    }

    // ---- bulk: sum of -clip(log(1-conf)) over ALL cells (loaded at top) ----
    {
        float local = 0.f;
        if (hasc)
            local = -(flog(1.f - cv.x) + flog(1.f - cv.y) +
                      flog(1.f - cv.z) + flog(1.f - cv.w));
        local = wred(local);
        if ((t & 63) == 0) atomicAdd(&s_acc[0], local);
    }
    __syncthreads();

    // ---- plain-store this block's partials (no init of ws required) ----
    if (t < 11) partials[blockIdx.x * 16 + t] = s_acc[t];
}

__global__ __launch_bounds__(NBLK) void reduce_kernel(
    const float* __restrict__ partials, float* __restrict__ out)
{
    __shared__ float s_r[4][11];
    const int t = threadIdx.x;           // one thread per block-slot
    float v[11];
    #pragma unroll
    for (int j = 0; j < 11; ++j) v[j] = partials[t * 16 + j];
    #pragma unroll
    for (int j = 0; j < 11; ++j) v[j] = wred(v[j]);
    const int lane = t & 63, w = t >> 6;
    if (lane == 0) {
        #pragma unroll
        for (int j = 0; j < 11; ++j) s_r[w][j] = v[j];
    }
    __syncthreads();
    if (t == 0) {
        float a[11];
        #pragma unroll
        for (int j = 0; j < 11; ++j)
            a[j] = s_r[0][j] + s_r[1][j] + s_r[2][j] + s_r[3][j];
        float n_obj   = a[9];
        float n_kill  = a[10];
        float inv_obj = 1.f / n_obj;
        float n_noobj = (float)Mv - n_kill;
        float loss_coord = (a[1] + a[2] + a[3] + a[4]) * inv_obj;
        float loss_conf  = a[5] * inv_obj + 100.f * (a[0] - a[7]) / n_noobj;
        float loss_cls   = (a[8] + a[6]) * inv_obj / (float)Cv;
        out[0] = loss_coord + loss_conf + loss_cls;
    }
}

extern "C" void kernel_launch(void* const* d_in, const int* in_sizes, int n_in,
                              void* d_out, int out_size, void* d_ws, size_t ws_size,
                              hipStream_t stream) {
    // setup_inputs order: 0:pred_boxes(unused) 1:pred_cls 2:center_x 3:center_y
    //                     4:width 5:height 6:confidence 7:anchors 8:target
    const float* pred_cls   = (const float*)d_in[1];
    const float* center_x   = (const float*)d_in[2];
    const float* center_y   = (const float*)d_in[3];
    const float* width_     = (const float*)d_in[4];
    const float* height_    = (const float*)d_in[5];
    const float* confidence = (const float*)d_in[6];
    const float* anchors    = (const float*)d_in[7];
    const float* target     = (const float*)d_in[8];
    float* partials = (float*)d_ws;   // 256 blocks × 16 floats = 16 KB

    main_kernel<<<NBLK, NTHR, 0, stream>>>(pred_cls, center_x, center_y, width_,
                                           height_, confidence, anchors, target,
                                           partials);
    reduce_kernel<<<1, NBLK, 0, stream>>>(partials, (float*)d_out);
}